// Round 2
// baseline (164.939 us; speedup 1.0000x reference)
//
#include <hip/hip_runtime.h>
#include <hip/hip_bf16.h>

#define TT 8000
#define BB 64
#define NBINS 24

// ======================= f64 helpers (decision-grade precision) =======================
__device__ __forceinline__ double delta_at(const double* __restrict__ e, int t){
  // delta[0]=0, delta[t]=|e[t]-e[t-1]|
  return (t <= 0) ? 0.0 : fabs(e[t] - e[t-1]);
}
// sliding mean of delta over window [t-half, t+half], zero-padded, divided by k
__device__ __forceinline__ double win_at(const double* __restrict__ e, int t, int half, double k){
  double s = 0.0;
  int j0 = t - half, j1 = t + half;
  if (j0 < 0) j0 = 0;
  if (j1 > TT - 1) j1 = TT - 1;
  for (int j = j0; j <= j1; ++j) s += delta_at(e, j);
  return s / k;
}
__device__ __forceinline__ double lr_at(const double* __restrict__ e, int t){ return win_at(e, t, 2, 5.0); }
__device__ __forceinline__ double bs_at(const double* __restrict__ e, int t){ return win_at(e, t, 3, 7.0); }

// =================== K1: energy = mean(mel, axis=-1) in f64 ====================
__global__ __launch_bounds__(256) void k_energy(const float* __restrict__ mel,
                                                double* __restrict__ e_bt){
  int r = blockIdx.x * 256 + threadIdx.x;           // [0, BB*TT)
  const float4* p = (const float4*)(mel + (size_t)r * 80);
  double s = 0.0;
  #pragma unroll
  for (int j = 0; j < 20; ++j){
    float4 v = p[j];
    s += (double)v.x; s += (double)v.y; s += (double)v.z; s += (double)v.w;
  }
  e_bt[r] = s / 80.0;
}

// =================== K2: mu, sd (ddof=1) per row, f64 block reduce ====================
__global__ __launch_bounds__(1024) void k_musd(const double* __restrict__ e_all,
                                               double* __restrict__ mu_, double* __restrict__ sd_){
  __shared__ double red[1024];
  __shared__ double mu_s;
  int b = blockIdx.x, tid = threadIdx.x;
  const double* e = e_all + (size_t)b * TT;
  double s = 0.0;
  for (int t = tid; t < TT; t += 1024) s += e[t];
  red[tid] = s; __syncthreads();
  for (int off = 512; off > 0; off >>= 1){
    if (tid < off) red[tid] += red[tid + off];
    __syncthreads();
  }
  if (tid == 0) mu_s = red[0] / 8000.0;
  __syncthreads();
  double mu = mu_s;
  double s2 = 0.0;
  for (int t = tid; t < TT; t += 1024){ double c = e[t] - mu; s2 += c * c; }
  red[tid] = s2; __syncthreads();
  for (int off = 512; off > 0; off >>= 1){
    if (tid < off) red[tid] += red[tid + off];
    __syncthreads();
  }
  if (tid == 0){
    double var = red[0] / 7999.0;
    double sd = sqrt(var);
    if (sd < 1e-6) sd = 1e-6;
    mu_[b] = mu; sd_[b] = sd;
  }
}

// =================== K3: exact f64 quantiles via bitonic sort ====================
__device__ void bitonic8192d(double* buf, int tid){
  for (int k = 2; k <= 8192; k <<= 1){
    for (int j = k >> 1; j > 0; j >>= 1){
      __syncthreads();
      for (int q = tid; q < 4096; q += 1024){
        int i = ((q & ~(j - 1)) << 1) | (q & (j - 1));
        int ix = i | j;
        double a = buf[i], c = buf[ix];
        bool up = ((i & k) == 0);
        if ((a > c) == up){ buf[i] = c; buf[ix] = a; }
      }
    }
  }
  __syncthreads();
}

// numpy _lerp: t<0.5 -> a + (b-a)*t ; t>=0.5 -> b - (b-a)*(1-t)
__device__ __forceinline__ double np_lerp(double a, double b, double t){
  double d = b - a;
  return (t >= 0.5) ? (b - d * (1.0 - t)) : (a + d * t);
}

// grid = BB*2: blockIdx.x>>1 = row, &1 = which array (0: delta -> dth, 1: bs -> bth)
__global__ __launch_bounds__(1024) void k_quant(const double* __restrict__ e_all,
                                                double* __restrict__ dth,
                                                double* __restrict__ bth){
  __shared__ double buf[8192];                      // 64 KB
  int b = blockIdx.x >> 1, arr = blockIdx.x & 1, tid = threadIdx.x;
  const double* e = e_all + (size_t)b * TT;
  const double INF = __builtin_inf();
  for (int t = tid; t < 8192; t += 1024)
    buf[t] = (t < TT) ? (arr ? bs_at(e, t) : delta_at(e, t)) : INF;
  bitonic8192d(buf, tid);
  if (tid == 0){
    double q = arr ? 0.75 : 0.35;
    double vi = q * 7999.0;                         // f64 virtual index
    int lo = (int)floor(vi);
    double g = vi - (double)lo;
    double thr = np_lerp(buf[lo], buf[lo + 1], g);
    if (arr) bth[b] = thr; else dth[b] = thr;
  }
}

// =================== K4: flags, progress, stats, trace ====================
__device__ void feat_at_d(int i, const unsigned char* flags, const double* prog,
                          const double* e, double* f){
  unsigned fl = flags[i];
  f[0] = (fl & 1) ? 1.0 : 0.0;                      // pause
  f[1] = lr_at(e, i);                               // local_rate
  f[2] = (fl & 4) ? 1.0 : 0.0;                      // bev
  double u = (i == TT - 1) ? 1.0 : (double)i * (1.0 / 7999.0);
  f[3] = prog[i] - u;                               // seg_bias
  f[4] = (fl & 2) ? 1.0 : 0.0;                      // voiced
}

__global__ __launch_bounds__(1024) void k_final(const double* __restrict__ e_all,
     const double* __restrict__ mu_, const double* __restrict__ sd_,
     const double* __restrict__ dth_, const double* __restrict__ bth_,
     float* __restrict__ out){
  __shared__ double prog[TT];                       // 64 KB
  __shared__ unsigned char flags[TT];               // 8 KB
  __shared__ int waveTot[16], waveOff[16];
  __shared__ int cnt[5];     // 0:pause ones 1:pause runs 2:speech runs 3:voiced 4:bev
  __shared__ double totalF;
  int b = blockIdx.x, tid = threadIdx.x;
  const double* e = e_all + (size_t)b * TT;
  double mu = mu_[b], sd = sd_[b], dthr = dth_[b], bthr = bth_[b];
  if (tid < 5) cnt[tid] = 0;
  __syncthreads();
  int t0 = tid * 8;
  bool act = (t0 < TT);
  if (act){
    for (int k = 0; k < 8; ++k){
      int t = t0 + k;
      double z = (e[t] - mu) / sd;
      bool pause  = (z <= -0.5) && (delta_at(e, t) <= dthr);
      bool voiced = (z > -0.1);
      bool bev    = (bs_at(e, t) >= bthr);
      flags[t] = (unsigned char)((pause ? 1 : 0) | (voiced ? 2 : 0) | (bev ? 4 : 0));
    }
  }
  __syncthreads();
  int local_speech = 0;
  if (act){
    int cp = 0, crp = 0, crs = 0, cv = 0, cb = 0;
    for (int k = 0; k < 8; ++k){
      int t = t0 + k;
      unsigned f = flags[t];
      bool pause = (f & 1) != 0;
      bool prevP = (t > 0) ? ((flags[t-1] & 1) != 0) : false;
      cp += pause ? 1 : 0; cv += (f >> 1) & 1; cb += (f >> 2) & 1;
      if (pause && (t == 0 || !prevP)) crp++;       // pause run start
      if (!pause && (t == 0 || prevP)) crs++;       // speech run start
      local_speech += pause ? 0 : 1;
    }
    atomicAdd(&cnt[0], cp); atomicAdd(&cnt[1], crp); atomicAdd(&cnt[2], crs);
    atomicAdd(&cnt[3], cv); atomicAdd(&cnt[4], cb);
  }
  // block-wide inclusive scan of per-thread speech counts (integers -> exact)
  int lane = tid & 63, wid = tid >> 6;
  int inc = local_speech;
  #pragma unroll
  for (int d = 1; d < 64; d <<= 1){
    int nb = __shfl_up(inc, d, 64);
    if (lane >= d) inc += nb;
  }
  if (lane == 63) waveTot[wid] = inc;
  __syncthreads();
  if (tid == 0){
    int acc = 0;
    for (int w = 0; w < 16; ++w){ waveOff[w] = acc; acc += waveTot[w]; }
    totalF = (acc > 1) ? (double)acc : 1.0;
  }
  __syncthreads();
  if (act){
    int run = waveOff[wid] + (inc - local_speech);
    double tf = totalF;
    for (int k = 0; k < 8; ++k){
      int t = t0 + k;
      run += (flags[t] & 1) ? 0 : 1;
      prog[t] = (double)run / tf;
    }
  }
  __syncthreads();
  if (tid == 0){
    float onesP = (float)cnt[0];
    float onesS = (float)(TT - cnt[0]);
    float* st = out + b * 6;
    st[0] = onesP / 8000.0f;
    st[1] = (cnt[1] > 0) ? (onesP / fmaxf((float)cnt[1], 1.0f)) : 0.0f;
    st[2] = (cnt[2] > 0) ? (onesS / fmaxf((float)cnt[2], 1.0f)) : 0.0f;
    st[3] = (float)(lr_at(e, TT - 1) - lr_at(e, 0));
    st[4] = ((float)cnt[4]) / 8000.0f;
    st[5] = ((float)cnt[3]) / 8000.0f;
  }
  if (tid < NBINS){
    double target = (tid == NBINS - 1) ? 1.0 : (double)tid * (1.0 / 23.0);
    int lo = 0, hi = TT;                            // searchsorted side='left'
    while (lo < hi){ int mid = (lo + hi) >> 1; if (prog[mid] < target) lo = mid + 1; else hi = mid; }
    int right = lo;
    int li = right - 1; li = li < 0 ? 0 : (li > TT-1 ? TT-1 : li);
    int ri = right;     ri = ri < 0 ? 0 : (ri > TT-1 ? TT-1 : ri);
    double pl = prog[li], pr = prog[ri];
    double denom = fabs(pr - pl); if (denom < 1e-6) denom = 1e-6;
    double alpha = (target - pl) / denom;
    if (alpha < 0.0) alpha = 0.0;
    if (alpha > 1.0) alpha = 1.0;
    if (right <= 0) alpha = 0.0;
    else if (right >= TT) alpha = 1.0;
    double fL[5], fR[5];
    feat_at_d(li, flags, prog, e, fL);
    feat_at_d(ri, flags, prog, e, fR);
    double om = 1.0 - alpha;
    float* tr = out + BB * 6 + ((size_t)b * NBINS + tid) * 5;
    #pragma unroll
    for (int f = 0; f < 5; ++f)
      tr[f] = (float)(fL[f] * om + fR[f] * alpha);
  }
}

extern "C" void kernel_launch(void* const* d_in, const int* in_sizes, int n_in,
                              void* d_out, int out_size, void* d_ws, size_t ws_size,
                              hipStream_t stream){
  const float* mel = (const float*)d_in[0];
  float* out = (float*)d_out;
  double* ws = (double*)d_ws;
  double* e_bt = ws;                 // 512000 doubles (4 MB)
  double* mu   = ws + 512000;        // 64
  double* sd   = ws + 512064;        // 64
  double* dth  = ws + 512128;        // 64
  double* bth  = ws + 512192;        // 64   (total ~4.1 MB of d_ws)

  hipLaunchKernelGGL(k_energy, dim3((BB*TT)/256), dim3(256), 0, stream, mel, e_bt);
  hipLaunchKernelGGL(k_musd,   dim3(BB),   dim3(1024), 0, stream, e_bt, mu, sd);
  hipLaunchKernelGGL(k_quant,  dim3(BB*2), dim3(1024), 0, stream, e_bt, dth, bth);
  hipLaunchKernelGGL(k_final,  dim3(BB),   dim3(1024), 0, stream, e_bt, mu, sd, dth, bth, out);
}

// Round 3
// 146.029 us; speedup vs baseline: 1.1295x; 1.1295x over previous
//
#include <hip/hip_runtime.h>
#include <hip/hip_bf16.h>

#define TT 8000
#define BB 64
#define NBINS 24
#define CAP 256

// ======================= f64 helpers =======================
__device__ __forceinline__ double dlt(const double* __restrict__ e, int t){
  return (t <= 0) ? 0.0 : fabs(e[t] - e[t-1]);
}
__device__ __forceinline__ double winsum(const double* __restrict__ e, int t, int half){
  int j0 = t - half; if (j0 < 0) j0 = 0;
  int j1 = t + half; if (j1 > TT - 1) j1 = TT - 1;
  double s = 0.0;
  for (int j = j0; j <= j1; ++j) s += dlt(e, j);
  return s;
}
__device__ __forceinline__ double evalA(const double* __restrict__ e, int t, int arr){
  return arr ? (winsum(e, t, 3) / 7.0) : dlt(e, t);
}
// numpy _lerp: t<0.5 -> a + (b-a)*t ; t>=0.5 -> b - (b-a)*(1-t)
__device__ __forceinline__ double np_lerp(double a, double b, double t){
  double d = b - a;
  return (t >= 0.5) ? (b - d * (1.0 - t)) : (a + d * t);
}
__device__ __forceinline__ double wred_sum(double v){
  #pragma unroll
  for (int o = 32; o; o >>= 1) v += __shfl_down(v, o, 64);
  return v;
}

// =================== K1: energy = mean(mel, axis=-1) in f64 ====================
__global__ __launch_bounds__(256) void k_energy(const float* __restrict__ mel,
                                                double* __restrict__ e_bt){
  int r = blockIdx.x * 256 + threadIdx.x;           // [0, BB*TT)
  const float4* p = (const float4*)(mel + (size_t)r * 80);
  double s = 0.0;
  #pragma unroll
  for (int j = 0; j < 20; ++j){
    float4 v = p[j];
    s += (double)v.x; s += (double)v.y; s += (double)v.z; s += (double)v.w;
  }
  e_bt[r] = s / 80.0;
}

// =================== K2: everything else, one block per row ====================
__global__ __launch_bounds__(1024) void k_fused(const double* __restrict__ e_all,
                                                float* __restrict__ out){
  __shared__ double e_s[TT];            // 64000 B
  __shared__ unsigned short runs[TT];   // 16000 B
  __shared__ unsigned char flags[TT];   //  8000 B
  __shared__ int hist4[1024];           //  4096 B (4 sub-histograms of 256)
  __shared__ int histA[256];            //  1024 B
  __shared__ int histB[256];            //  1024 B
  __shared__ double cand[CAP];          //  2048 B
  __shared__ double red16[16];
  __shared__ double scD[8];             // 0:mu 1:sd 2:dthr 3:bthr 4:olo 5:ohi 6:tf
  __shared__ int    scI[4];             // 0:binr 1:binr1 2:candN
  __shared__ int    waveTot[16], waveOff[16];
  __shared__ int    cnt5[5];

  const int b = blockIdx.x, tid = threadIdx.x;
  const int lane = tid & 63, wid = tid >> 6;
  const double* eg = e_all + (size_t)b * TT;

  for (int t = tid; t < TT; t += 1024) e_s[t] = eg[t];
  __syncthreads();

  // ---- mu ----
  double ps = 0.0;
  for (int t = tid; t < TT; t += 1024) ps += e_s[t];
  double w = wred_sum(ps);
  if (lane == 0) red16[wid] = w;
  __syncthreads();
  if (tid < 64){
    double x = (tid < 16) ? red16[tid] : 0.0;
    x = wred_sum(x);
    if (tid == 0) scD[0] = x / 8000.0;
  }
  __syncthreads();
  const double mu = scD[0];
  // ---- sd (ddof=1) ----
  double p2 = 0.0;
  for (int t = tid; t < TT; t += 1024){ double c = e_s[t] - mu; p2 += c * c; }
  w = wred_sum(p2);
  if (lane == 0) red16[wid] = w;
  __syncthreads();
  if (tid < 64){
    double x = (tid < 16) ? red16[tid] : 0.0;
    x = wred_sum(x);
    if (tid == 0){
      double sd = sqrt(x / 7999.0);
      scD[1] = (sd < 1e-6) ? 1e-6 : sd;
    }
  }
  __syncthreads();
  const double sd = scD[1];

  // ---- exact quantiles via bit-prefix radix select (ranks r, r+1) ----
  for (int arr = 0; arr < 2; ++arr){
    const int r = arr ? 5999 : 2799;                // 0.75*7999 / 0.35*7999 floors
    int s = 64, sc = 56;
    long long prefix = 0;
    int below = 0;
    bool done = false;
    while (!done){
      hist4[tid] = 0;
      if (tid == 0){ scI[0] = 0; scI[1] = 0; scI[2] = 0; }
      __syncthreads();
      for (int t = tid; t < TT; t += 1024){
        double v = evalA(e_s, t, arr);
        long long key = __double_as_longlong(v);    // v>=0 -> bit order == value order
        bool c = (s >= 64) || ((key >> s) == prefix);
        if (c) atomicAdd(&hist4[((wid & 3) << 8) + (int)((key >> sc) & 255)], 1);
      }
      __syncthreads();
      if (tid < 256)
        histA[tid] = hist4[tid] + hist4[256 + tid] + hist4[512 + tid] + hist4[768 + tid];
      __syncthreads();
      // inclusive scan over 256 bins (Hillis-Steele, ping-pong)
      int* src = histA; int* dst = histB;
      for (int d = 1; d < 256; d <<= 1){
        if (tid < 256) dst[tid] = src[tid] + ((tid >= d) ? src[tid - d] : 0);
        __syncthreads();
        int* tmp = src; src = dst; dst = tmp;
      }
      const int rr = r - below;                     // rank among candidates
      if (tid < 256){
        int Pt = src[tid], Pm = tid ? src[tid - 1] : 0;
        if (rr  >= Pm && rr  < Pt) scI[0] = tid;    // bin holding rank rr
        if (rr+1 >= Pm && rr+1 < Pt) scI[1] = tid;  // bin holding rank rr+1
      }
      __syncthreads();
      const int binr = scI[0], binr1 = scI[1];
      const int Pbm = binr ? src[binr - 1] : 0;
      const int cntR = src[binr1] - Pbm;            // bins between binr,binr1 are empty
      if (cntR <= CAP){
        // collect candidates, exact rank by counting
        for (int t = tid; t < TT; t += 1024){
          double v = evalA(e_s, t, arr);
          long long key = __double_as_longlong(v);
          bool c = (s >= 64) || ((key >> s) == prefix);
          if (c){
            int bi = (int)((key >> sc) & 255);
            if (bi == binr || bi == binr1){
              int ix = atomicAdd(&scI[2], 1);
              if (ix < CAP) cand[ix] = v;
            }
          }
        }
        __syncthreads();
        int n = scI[2]; if (n > CAP) n = CAP;
        int tgt = rr - Pbm;
        if (tid < n){
          double mv = cand[tid];
          int rk = 0;
          for (int j = 0; j < n; ++j){
            double cj = cand[j];
            rk += (cj < mv || (cj == mv && j < tid)) ? 1 : 0;
          }
          if (rk == tgt)     scD[4] = mv;
          if (rk == tgt + 1) scD[5] = mv;
        }
        done = true;
        __syncthreads();
      } else if (sc == 0){
        // >CAP identical full keys: value determined exactly by key
        if (tid == 0){
          scD[4] = __longlong_as_double((prefix << 8) | (long long)binr);
          scD[5] = __longlong_as_double((prefix << 8) | (long long)binr1);
        }
        done = true;
        __syncthreads();
      } else if (binr == binr1){
        prefix = (s >= 64) ? (long long)binr : ((prefix << 8) | (long long)binr);
        below += Pbm;
        s = sc; sc -= 8;
        __syncthreads();                            // protect src reads vs next zeroing
      } else {
        // ranks straddle two huge duplicate groups: rank rr = max(binr), rr+1 = min(binr1)
        double mx = -1.0, mn = __builtin_inf();
        for (int t = tid; t < TT; t += 1024){
          double v = evalA(e_s, t, arr);
          long long key = __double_as_longlong(v);
          bool c = (s >= 64) || ((key >> s) == prefix);
          if (c){
            int bi = (int)((key >> sc) & 255);
            if (bi == binr)  mx = fmax(mx, v);
            if (bi == binr1) mn = fmin(mn, v);
          }
        }
        double wv = mx;
        #pragma unroll
        for (int o = 32; o; o >>= 1) wv = fmax(wv, __shfl_down(wv, o, 64));
        if (lane == 0) red16[wid] = wv;
        __syncthreads();
        if (tid == 0){
          double m = red16[0];
          for (int i = 1; i < 16; ++i) m = fmax(m, red16[i]);
          scD[4] = m;
        }
        __syncthreads();
        wv = mn;
        #pragma unroll
        for (int o = 32; o; o >>= 1) wv = fmin(wv, __shfl_down(wv, o, 64));
        if (lane == 0) red16[wid] = wv;
        __syncthreads();
        if (tid == 0){
          double m = red16[0];
          for (int i = 1; i < 16; ++i) m = fmin(m, red16[i]);
          scD[5] = m;
        }
        done = true;
        __syncthreads();
      }
    }
    if (tid == 0){
      double vi = (arr ? 0.75 : 0.35) * 7999.0;
      double g = vi - floor(vi);
      scD[2 + arr] = np_lerp(scD[4], scD[5], g);    // numpy _lerp semantics
    }
    __syncthreads();
  }
  const double dthr = scD[2], bthr = scD[3];

  // ---- flags ----
  if (tid < 5) cnt5[tid] = 0;
  __syncthreads();
  const int t0 = tid * 8;
  const bool act = (t0 < TT);
  if (act){
    for (int k = 0; k < 8; ++k){
      int t = t0 + k;
      double z = (e_s[t] - mu) / sd;
      bool pause  = (z <= -0.5) && (dlt(e_s, t) <= dthr);
      bool voiced = (z > -0.1);
      bool bev    = ((winsum(e_s, t, 3) / 7.0) >= bthr);
      flags[t] = (unsigned char)((pause ? 1 : 0) | (voiced ? 2 : 0) | (bev ? 4 : 0));
    }
  }
  __syncthreads();
  // ---- counts + speech scan ----
  int local_speech = 0;
  if (act){
    int cp = 0, crp = 0, crs = 0, cv = 0, cb = 0;
    for (int k = 0; k < 8; ++k){
      int t = t0 + k;
      unsigned f = flags[t];
      bool pause = (f & 1) != 0;
      bool prevP = (t > 0) ? ((flags[t-1] & 1) != 0) : false;
      cp += pause ? 1 : 0; cv += (f >> 1) & 1; cb += (f >> 2) & 1;
      if (pause && (t == 0 || !prevP)) crp++;
      if (!pause && (t == 0 || prevP)) crs++;
      local_speech += pause ? 0 : 1;
    }
    atomicAdd(&cnt5[0], cp); atomicAdd(&cnt5[1], crp); atomicAdd(&cnt5[2], crs);
    atomicAdd(&cnt5[3], cv); atomicAdd(&cnt5[4], cb);
  }
  int inc = local_speech;
  #pragma unroll
  for (int d = 1; d < 64; d <<= 1){
    int nb = __shfl_up(inc, d, 64);
    if (lane >= d) inc += nb;
  }
  if (lane == 63) waveTot[wid] = inc;
  __syncthreads();
  if (tid == 0){
    int acc = 0;
    for (int w2 = 0; w2 < 16; ++w2){ waveOff[w2] = acc; acc += waveTot[w2]; }
    scD[6] = (acc > 1) ? (double)acc : 1.0;
  }
  __syncthreads();
  const double tf = scD[6];
  if (act){
    int run = waveOff[wid] + (inc - local_speech);
    for (int k = 0; k < 8; ++k){
      int t = t0 + k;
      run += (flags[t] & 1) ? 0 : 1;
      runs[t] = (unsigned short)run;
    }
  }
  __syncthreads();
  // ---- stats ----
  if (tid == 0){
    float onesP = (float)cnt5[0];
    float onesS = (float)(TT - cnt5[0]);
    float* st = out + b * 6;
    st[0] = onesP / 8000.0f;
    st[1] = (cnt5[1] > 0) ? (onesP / fmaxf((float)cnt5[1], 1.0f)) : 0.0f;
    st[2] = (cnt5[2] > 0) ? (onesS / fmaxf((float)cnt5[2], 1.0f)) : 0.0f;
    st[3] = (float)(winsum(e_s, TT - 1, 2) / 5.0 - winsum(e_s, 0, 2) / 5.0);
    st[4] = ((float)cnt5[4]) / 8000.0f;
    st[5] = ((float)cnt5[3]) / 8000.0f;
  }
  // ---- trace: searchsorted + lerp ----
  if (tid < NBINS){
    double target = (tid == NBINS - 1) ? 1.0 : (double)tid * (1.0 / 23.0);
    int lo = 0, hi = TT;
    while (lo < hi){
      int mid = (lo + hi) >> 1;
      double pm = (double)runs[mid] / tf;
      if (pm < target) lo = mid + 1; else hi = mid;
    }
    int right = lo;
    int li = right - 1; li = li < 0 ? 0 : (li > TT-1 ? TT-1 : li);
    int ri = right;     ri = ri < 0 ? 0 : (ri > TT-1 ? TT-1 : ri);
    double pl = (double)runs[li] / tf, pr = (double)runs[ri] / tf;
    double denom = fabs(pr - pl); if (denom < 1e-6) denom = 1e-6;
    double alpha = (target - pl) / denom;
    if (alpha < 0.0) alpha = 0.0;
    if (alpha > 1.0) alpha = 1.0;
    if (right <= 0) alpha = 0.0;
    else if (right >= TT) alpha = 1.0;
    double fL[5], fR[5];
    {
      int idx2[2] = {li, ri};
      for (int sdx = 0; sdx < 2; ++sdx){
        int i = idx2[sdx];
        double* f = sdx ? fR : fL;
        unsigned fl = flags[i];
        f[0] = (fl & 1) ? 1.0 : 0.0;
        f[1] = winsum(e_s, i, 2) / 5.0;
        f[2] = (fl & 4) ? 1.0 : 0.0;
        double u = (i == TT - 1) ? 1.0 : (double)i * (1.0 / 7999.0);
        f[3] = (double)runs[i] / tf - u;
        f[4] = (fl & 2) ? 1.0 : 0.0;
      }
    }
    double om = 1.0 - alpha;
    float* tr = out + BB * 6 + ((size_t)b * NBINS + tid) * 5;
    #pragma unroll
    for (int f = 0; f < 5; ++f)
      tr[f] = (float)(fL[f] * om + fR[f] * alpha);
  }
}

extern "C" void kernel_launch(void* const* d_in, const int* in_sizes, int n_in,
                              void* d_out, int out_size, void* d_ws, size_t ws_size,
                              hipStream_t stream){
  const float* mel = (const float*)d_in[0];
  float* out = (float*)d_out;
  double* e_bt = (double*)d_ws;      // 512000 doubles = 4 MB

  hipLaunchKernelGGL(k_energy, dim3((BB*TT)/256), dim3(256), 0, stream, mel, e_bt);
  hipLaunchKernelGGL(k_fused,  dim3(BB),          dim3(1024), 0, stream, e_bt, out);
}

// Round 4
// 85.760 us; speedup vs baseline: 1.9233x; 1.7028x over previous
//
#include <hip/hip_runtime.h>
#include <hip/hip_bf16.h>

#define TT 8000
#define BB 64
#define NBINS 24
#define CAP 256
#define NS 8   // stripes: t = tid + s*1024

// =================== K1: energy = mean(mel, axis=-1) in f64 ====================
__global__ __launch_bounds__(256) void k_energy(const float* __restrict__ mel,
                                                double* __restrict__ e_bt){
  int r = blockIdx.x * 256 + threadIdx.x;           // [0, BB*TT)
  const float4* p = (const float4*)(mel + (size_t)r * 80);
  double s = 0.0;
  #pragma unroll
  for (int j = 0; j < 20; ++j){
    float4 v = p[j];
    s += (double)v.x; s += (double)v.y; s += (double)v.z; s += (double)v.w;
  }
  e_bt[r] = s / 80.0;
}

// Exact two-order-statistic select (ranks RNK, RNK+1) by value-space bisection on
// register-cached values. Zero LDS atomics in the narrowing loop. All branch
// conditions are block-uniform (derived from shared broadcasts).
#define QSELECT(VALS, RNK, OUTIDX, QG)                                          \
  {                                                                             \
    double m_ = -1.0;                                                           \
    _Pragma("unroll")                                                           \
    for (int s = 0; s < NS; ++s){                                               \
      int t = tid + (s << 10);                                                  \
      if (t < TT && VALS[s] > m_) m_ = VALS[s];                                 \
    }                                                                           \
    _Pragma("unroll")                                                           \
    for (int o = 32; o; o >>= 1){ double x = __shfl_down(m_, o, 64); if (x > m_) m_ = x; } \
    if (lane == 0) redD[wid] = m_;                                              \
    __syncthreads();                                                            \
    if (tid == 0){ double a = redD[0]; for (int i = 1; i < 16; ++i) if (redD[i] > a) a = redD[i]; scD[4] = a; } \
    __syncthreads();                                                            \
    double lo_ = -0.5, hi_ = scD[4];                                            \
    int cl_ = 0, ch_ = 8000;                                                    \
    for (;;){                                                                   \
      if (ch_ - cl_ <= CAP){                                                    \
        if (tid == 0) scI[1] = 0;                                               \
        __syncthreads();                                                        \
        _Pragma("unroll")                                                       \
        for (int s = 0; s < NS; ++s){                                           \
          int t = tid + (s << 10);                                              \
          if (t < TT){ double v = VALS[s];                                      \
            if (v > lo_ && v <= hi_){ int ix = atomicAdd(&scI[1], 1); if (ix < CAP) cand[ix] = v; } } \
        }                                                                       \
        __syncthreads();                                                        \
        int n = scI[1]; if (n > CAP) n = CAP;                                   \
        int tgt = (RNK) - cl_;                                                  \
        if (tid < n){                                                           \
          double mv = cand[tid];                                                \
          int rk = 0;                                                           \
          for (int j = 0; j < n; ++j){ double cj = cand[j];                     \
            rk += (cj < mv || (cj == mv && j < tid)) ? 1 : 0; }                 \
          if (rk == tgt)     scD[4] = mv;                                       \
          if (rk == tgt + 1) scD[5] = mv;                                       \
        }                                                                       \
        __syncthreads();                                                        \
        break;                                                                  \
      }                                                                         \
      double mid_ = 0.5 * (lo_ + hi_);                                          \
      if (!(mid_ > lo_ && mid_ < hi_)){                                         \
        if (tid == 0){ scD[4] = hi_; scD[5] = hi_; }                            \
        __syncthreads();                                                        \
        break;                                                                  \
      }                                                                         \
      int c_ = 0;                                                               \
      _Pragma("unroll")                                                         \
      for (int s = 0; s < NS; ++s){                                             \
        int t = tid + (s << 10);                                                \
        if (t < TT && VALS[s] <= mid_) c_++;                                    \
      }                                                                         \
      _Pragma("unroll")                                                         \
      for (int o = 32; o; o >>= 1) c_ += __shfl_down(c_, o, 64);                \
      if (lane == 0) redI[wid] = c_;                                            \
      __syncthreads();                                                          \
      if (tid == 0){ int a = 0; for (int i = 0; i < 16; ++i) a += redI[i]; scI[0] = a; } \
      __syncthreads();                                                          \
      int ct_ = scI[0];                                                         \
      if (ct_ <= (RNK)){ lo_ = mid_; cl_ = ct_; }                               \
      else if (ct_ >= (RNK) + 2){ hi_ = mid_; ch_ = ct_; }                      \
      else {                                                                    \
        double mx_ = -1.0, mn_ = 1e300;                                         \
        _Pragma("unroll")                                                       \
        for (int s = 0; s < NS; ++s){                                           \
          int t = tid + (s << 10);                                              \
          if (t < TT){ double v = VALS[s];                                      \
            if (v <= mid_){ if (v > mx_) mx_ = v; } else { if (v < mn_) mn_ = v; } } \
        }                                                                       \
        _Pragma("unroll")                                                       \
        for (int o = 32; o; o >>= 1){ double x = __shfl_down(mx_, o, 64); if (x > mx_) mx_ = x; } \
        if (lane == 0) redD[wid] = mx_;                                         \
        __syncthreads();                                                        \
        if (tid == 0){ double a = redD[0]; for (int i = 1; i < 16; ++i) if (redD[i] > a) a = redD[i]; scD[4] = a; } \
        __syncthreads();                                                        \
        _Pragma("unroll")                                                       \
        for (int o = 32; o; o >>= 1){ double x = __shfl_down(mn_, o, 64); if (x < mn_) mn_ = x; } \
        if (lane == 0) redD[wid] = mn_;                                         \
        __syncthreads();                                                        \
        if (tid == 0){ double a = redD[0]; for (int i = 1; i < 16; ++i) if (redD[i] < a) a = redD[i]; scD[5] = a; } \
        __syncthreads();                                                        \
        break;                                                                  \
      }                                                                         \
    }                                                                           \
    if (tid == 0){                                                              \
      double d_ = scD[5] - scD[4];                                              \
      double g_ = (QG);                                                         \
      scD[OUTIDX] = (g_ >= 0.5) ? (scD[5] - d_ * (1.0 - g_)) : (scD[4] + d_ * g_); \
    }                                                                           \
    __syncthreads();                                                            \
  }

// =================== K2: one block per row, everything fused ====================
__global__ __launch_bounds__(1024) void k_row(const double* __restrict__ e_all,
                                              float* __restrict__ out){
  __shared__ double e_s[TT];            // 64000 B
  __shared__ double delta_s[TT];        // 64000 B
  __shared__ unsigned short runs[TT];   // 16000 B
  __shared__ unsigned char flags[TT];   //  8000 B
  __shared__ double cand[CAP];          //  2048 B
  __shared__ double redD[16];
  __shared__ int    redI[16];
  __shared__ double scD[8];             // 0:mu 1:sd 2:dthr 3:bthr 4:vlo 5:vhi 6:tf
  __shared__ int    scI[2];             // 0:count 1:candN
  __shared__ int    waveTot[16], waveOff[16], cnt5[5];

  const int b = blockIdx.x, tid = threadIdx.x;
  const int lane = tid & 63, wid = tid >> 6;
  const double* eg = e_all + (size_t)b * TT;

  double ev[NS], dv[NS], bv[NS];
  // ---- load e (striped: lane-consecutive -> 2-way LDS max) ----
  #pragma unroll
  for (int s = 0; s < NS; ++s){
    int t = tid + (s << 10);
    double e = (t < TT) ? eg[t] : 0.0;
    ev[s] = e;
    if (t < TT) e_s[t] = e;
  }
  __syncthreads();
  // ---- delta ----
  #pragma unroll
  for (int s = 0; s < NS; ++s){
    int t = tid + (s << 10);
    double d = 0.0;
    if (t > 0 && t < TT) d = fabs(e_s[t] - e_s[t-1]);
    dv[s] = d;
    if (t < TT) delta_s[t] = d;
  }
  __syncthreads();
  // ---- bs (window-7 mean), register-cached ----
  #pragma unroll
  for (int s = 0; s < NS; ++s){
    int t = tid + (s << 10);
    double sum = 0.0;
    if (t < TT){
      int j0 = t - 3; if (j0 < 0) j0 = 0;
      int j1 = t + 3; if (j1 > TT-1) j1 = TT-1;
      for (int j = j0; j <= j1; ++j) sum += delta_s[j];
    }
    bv[s] = sum / 7.0;
  }
  // ---- mu (two-pass with sd for np-f64 parity) ----
  double se = 0.0;
  #pragma unroll
  for (int s = 0; s < NS; ++s) se += ev[s];         // invalid slots are 0
  #pragma unroll
  for (int o = 32; o; o >>= 1) se += __shfl_down(se, o, 64);
  if (lane == 0) redD[wid] = se;
  __syncthreads();
  if (tid == 0){ double a = 0; for (int i = 0; i < 16; ++i) a += redD[i]; scD[0] = a / 8000.0; }
  __syncthreads();
  const double mu = scD[0];
  double se2 = 0.0;
  #pragma unroll
  for (int s = 0; s < NS; ++s){
    int t = tid + (s << 10);
    if (t < TT){ double c = ev[s] - mu; se2 += c * c; }
  }
  #pragma unroll
  for (int o = 32; o; o >>= 1) se2 += __shfl_down(se2, o, 64);
  if (lane == 0) redD[wid] = se2;
  __syncthreads();
  if (tid == 0){
    double a = 0; for (int i = 0; i < 16; ++i) a += redD[i];
    double sd = sqrt(a / 7999.0);
    scD[1] = (sd < 1e-6) ? 1e-6 : sd;
  }
  __syncthreads();
  const double sd = scD[1];

  // ---- exact quantiles (ranks 2799/2800 and 5999/6000) ----
  QSELECT(dv, 2799, 2, (0.35 * 7999.0 - 2799.0));
  QSELECT(bv, 5999, 3, (0.75 * 7999.0 - 5999.0));
  const double dthr = scD[2], bthr = scD[3];

  // ---- flags (striped, register inputs) ----
  if (tid < 5) cnt5[tid] = 0;
  #pragma unroll
  for (int s = 0; s < NS; ++s){
    int t = tid + (s << 10);
    if (t < TT){
      double z = (ev[s] - mu) / sd;
      bool pause  = (z <= -0.5) && (dv[s] <= dthr);
      bool voiced = (z > -0.1);
      bool bev    = (bv[s] >= bthr);
      flags[t] = (unsigned char)((pause ? 1 : 0) | (voiced ? 2 : 0) | (bev ? 4 : 0));
    }
  }
  __syncthreads();
  // ---- counts (wave-reduced, 16 leader atomics per counter) ----
  {
    int cp = 0, crp = 0, crs = 0, cv = 0, cb = 0;
    #pragma unroll
    for (int s = 0; s < NS; ++s){
      int t = tid + (s << 10);
      if (t < TT){
        unsigned f = flags[t];
        bool pause = (f & 1) != 0;
        bool prevP = (t > 0) ? ((flags[t-1] & 1) != 0) : false;
        cp += pause ? 1 : 0; cv += (f >> 1) & 1; cb += (f >> 2) & 1;
        if (pause && (t == 0 || !prevP)) crp++;
        if (!pause && (t == 0 || prevP)) crs++;
      }
    }
    #pragma unroll
    for (int o = 32; o; o >>= 1){
      cp += __shfl_down(cp, o, 64); crp += __shfl_down(crp, o, 64);
      crs += __shfl_down(crs, o, 64); cv += __shfl_down(cv, o, 64);
      cb += __shfl_down(cb, o, 64);
    }
    if (lane == 0){
      atomicAdd(&cnt5[0], cp); atomicAdd(&cnt5[1], crp); atomicAdd(&cnt5[2], crs);
      atomicAdd(&cnt5[3], cv); atomicAdd(&cnt5[4], cb);
    }
  }
  // ---- speech inclusive scan (contiguous-8 per thread; u8 reads cheap) ----
  const int t0 = tid * 8;
  int local_speech = 0;
  if (t0 < TT){
    #pragma unroll
    for (int k = 0; k < 8; ++k) local_speech += (flags[t0 + k] & 1) ? 0 : 1;
  }
  int inc = local_speech;
  #pragma unroll
  for (int d = 1; d < 64; d <<= 1){
    int nb = __shfl_up(inc, d, 64);
    if (lane >= d) inc += nb;
  }
  if (lane == 63) waveTot[wid] = inc;
  __syncthreads();
  if (tid == 0){
    int acc = 0;
    for (int w2 = 0; w2 < 16; ++w2){ waveOff[w2] = acc; acc += waveTot[w2]; }
    scD[6] = (acc > 1) ? (double)acc : 1.0;
  }
  __syncthreads();
  const double tf = scD[6];
  if (t0 < TT){
    int run = waveOff[wid] + (inc - local_speech);
    #pragma unroll
    for (int k = 0; k < 8; ++k){
      int t = t0 + k;
      run += (flags[t] & 1) ? 0 : 1;
      runs[t] = (unsigned short)run;
    }
  }
  __syncthreads();
  // ---- stats ----
  if (tid == 0){
    float onesP = (float)cnt5[0];
    float onesS = (float)(TT - cnt5[0]);
    float* st = out + b * 6;
    st[0] = onesP / 8000.0f;
    st[1] = (cnt5[1] > 0) ? (onesP / fmaxf((float)cnt5[1], 1.0f)) : 0.0f;
    st[2] = (cnt5[2] > 0) ? (onesS / fmaxf((float)cnt5[2], 1.0f)) : 0.0f;
    st[3] = (float)((delta_s[7997] + delta_s[7998] + delta_s[7999]) / 5.0
                  - (delta_s[0] + delta_s[1] + delta_s[2]) / 5.0);
    st[4] = ((float)cnt5[4]) / 8000.0f;
    st[5] = ((float)cnt5[3]) / 8000.0f;
  }
  // ---- trace: searchsorted + lerp ----
  if (tid < NBINS){
    double target = (tid == NBINS - 1) ? 1.0 : (double)tid * (1.0 / 23.0);
    int lo2 = 0, hi2 = TT;
    while (lo2 < hi2){
      int mid = (lo2 + hi2) >> 1;
      if ((double)runs[mid] / tf < target) lo2 = mid + 1; else hi2 = mid;
    }
    int right = lo2;
    int li = right - 1; if (li < 0) li = 0; if (li > TT-1) li = TT-1;
    int ri = right;     if (ri < 0) ri = 0; if (ri > TT-1) ri = TT-1;
    double pl = (double)runs[li] / tf, pr = (double)runs[ri] / tf;
    double denom = fabs(pr - pl); if (denom < 1e-6) denom = 1e-6;
    double alpha = (target - pl) / denom;
    if (alpha < 0.0) alpha = 0.0;
    if (alpha > 1.0) alpha = 1.0;
    if (right <= 0) alpha = 0.0;
    else if (right >= TT) alpha = 1.0;
    double fL[5], fR[5];
    for (int sdx = 0; sdx < 2; ++sdx){
      int i = sdx ? ri : li;
      double* f = sdx ? fR : fL;
      unsigned fl = flags[i];
      int j0 = i - 2; if (j0 < 0) j0 = 0;
      int j1 = i + 2; if (j1 > TT-1) j1 = TT-1;
      double ws = 0.0;
      for (int j = j0; j <= j1; ++j) ws += delta_s[j];
      f[0] = (fl & 1) ? 1.0 : 0.0;
      f[1] = ws / 5.0;
      f[2] = (fl & 4) ? 1.0 : 0.0;
      double u = (i == TT - 1) ? 1.0 : (double)i * (1.0 / 7999.0);
      f[3] = (double)runs[i] / tf - u;
      f[4] = (fl & 2) ? 1.0 : 0.0;
    }
    double om = 1.0 - alpha;
    float* tr = out + BB * 6 + ((size_t)b * NBINS + tid) * 5;
    #pragma unroll
    for (int f = 0; f < 5; ++f)
      tr[f] = (float)(fL[f] * om + fR[f] * alpha);
  }
}

extern "C" void kernel_launch(void* const* d_in, const int* in_sizes, int n_in,
                              void* d_out, int out_size, void* d_ws, size_t ws_size,
                              hipStream_t stream){
  const float* mel = (const float*)d_in[0];
  float* out = (float*)d_out;
  double* e_bt = (double*)d_ws;      // 512000 doubles = 4 MB

  hipLaunchKernelGGL(k_energy, dim3((BB*TT)/256), dim3(256), 0, stream, mel, e_bt);
  hipLaunchKernelGGL(k_row,    dim3(BB),          dim3(1024), 0, stream, e_bt, out);
}

// Round 5
// 53.395 us; speedup vs baseline: 3.0890x; 1.6061x over previous
//
#include <hip/hip_runtime.h>
#include <hip/hip_bf16.h>

#define TT 8000
#define BB 64
#define NBINS 24
#define CAP 256
#define NS 8     // stripes: t = tid + s*1024
#define NHB 1024 // histogram bins

// =================== K1: energy = mean(mel, axis=-1), LDS-staged coalesced ====================
// 8000 blocks x 256 threads; each block: 64 rows = 5120 f32 = 20 KB.
__global__ __launch_bounds__(256) void k_energy(const float* __restrict__ mel,
                                                double* __restrict__ e_bt){
  __shared__ float sm[5120];
  const int blk = blockIdx.x, tid = threadIdx.x;
  const float4* g = (const float4*)(mel + (size_t)blk * 5120);
  float4* s4 = (float4*)sm;
  #pragma unroll
  for (int j = 0; j < 5; ++j) s4[tid + j * 256] = g[tid + j * 256];
  __syncthreads();
  // thread k sums quarter-segment [20k, 20k+20)
  const float* p = sm + tid * 20;
  double s = 0.0;
  #pragma unroll
  for (int j = 0; j < 20; ++j) s += (double)p[j];
  s += __shfl_xor(s, 1, 64);
  s += __shfl_xor(s, 2, 64);
  if ((tid & 3) == 0) e_bt[(size_t)blk * 64 + (tid >> 2)] = s / 80.0;
}

// ---- exact two-order-statistic select (ranks RNK, RNK+1) ----
// Fast path: one-pass 1024-bin histogram + block scan + tiny collect.
// Fallback (heavy bin, >CAP candidates): value-space bisection (round-4 proven).
#define QUANT(VALS, RNK, OUTIDX, QG, MAXIDX)                                     \
  {                                                                              \
    const double maxv = scD[MAXIDX];                                             \
    if (maxv <= 0.0){                                                            \
      if (tid == 0) scD[OUTIDX] = 0.0;                                           \
      __syncthreads();                                                           \
    } else {                                                                     \
      const double scale = (double)NHB / maxv;                                   \
      if (tid < 8) scI[tid] = 0;                                                 \
      hist[tid] = 0;                                                             \
      __syncthreads();                                                           \
      _Pragma("unroll")                                                          \
      for (int s = 0; s < NS; ++s){                                              \
        int t = tid + (s << 10);                                                 \
        if (t < TT){                                                             \
          int bi = (int)(VALS[s] * scale); if (bi > NHB-1) bi = NHB-1;           \
          atomicAdd(&hist[bi], 1);                                               \
        }                                                                        \
      }                                                                          \
      __syncthreads();                                                           \
      const int h = hist[tid];                                                   \
      int inc = h;                                                               \
      _Pragma("unroll")                                                          \
      for (int d2 = 1; d2 < 64; d2 <<= 1){                                       \
        int nb = __shfl_up(inc, d2, 64);                                         \
        if (lane >= d2) inc += nb;                                               \
      }                                                                          \
      if (lane == 63) waveTot[wid] = inc;                                        \
      __syncthreads();                                                           \
      if (tid == 0){                                                             \
        int acc = 0;                                                             \
        for (int w2 = 0; w2 < 16; ++w2){ waveOff[w2] = acc; acc += waveTot[w2]; } \
      }                                                                          \
      __syncthreads();                                                           \
      {                                                                          \
        int P = waveOff[wid] + inc;   /* inclusive prefix for bin tid */         \
        if ((RNK)   >= P - h && (RNK)   < P){ scI[0] = tid; scI[2] = P - h; }    \
        if ((RNK)+1 >= P - h && (RNK)+1 < P){ scI[1] = tid; scI[3] = P; }        \
      }                                                                          \
      __syncthreads();                                                           \
      const int binr = scI[0], binr1 = scI[1], Pm = scI[2];                      \
      const int cwin = scI[3] - scI[2];                                          \
      if (cwin <= CAP){                                                          \
        _Pragma("unroll")                                                        \
        for (int s = 0; s < NS; ++s){                                            \
          int t = tid + (s << 10);                                               \
          if (t < TT){                                                           \
            int bi = (int)(VALS[s] * scale); if (bi > NHB-1) bi = NHB-1;         \
            if (bi >= binr && bi <= binr1){                                      \
              int ix = atomicAdd(&scI[4], 1);                                    \
              if (ix < CAP) cand[ix] = VALS[s];                                  \
            }                                                                    \
          }                                                                      \
        }                                                                        \
        __syncthreads();                                                         \
        int n = scI[4]; if (n > CAP) n = CAP;                                    \
        int tgt = (RNK) - Pm;                                                    \
        if (tid < n){                                                            \
          double mv = cand[tid];                                                 \
          int rk = 0;                                                            \
          for (int j = 0; j < n; ++j){ double cj = cand[j];                      \
            rk += (cj < mv || (cj == mv && j < tid)) ? 1 : 0; }                  \
          if (rk == tgt)     scD[4] = mv;                                        \
          if (rk == tgt + 1) scD[5] = mv;                                        \
        }                                                                        \
        __syncthreads();                                                         \
      } else {                                                                   \
        /* ---- fallback: value-space bisection (rare) ---- */                   \
        double lo_ = -0.5, hi_ = maxv;                                           \
        int cl_ = 0, ch_ = 8000;                                                 \
        for (;;){                                                                \
          if (ch_ - cl_ <= CAP){                                                 \
            if (tid == 0) scI[5] = 0;                                            \
            __syncthreads();                                                     \
            _Pragma("unroll")                                                    \
            for (int s = 0; s < NS; ++s){                                        \
              int t = tid + (s << 10);                                           \
              if (t < TT){ double v = VALS[s];                                   \
                if (v > lo_ && v <= hi_){ int ix = atomicAdd(&scI[5], 1);        \
                  if (ix < CAP) cand[ix] = v; } }                                \
            }                                                                    \
            __syncthreads();                                                     \
            int n = scI[5]; if (n > CAP) n = CAP;                                \
            int tgt = (RNK) - cl_;                                               \
            if (tid < n){                                                        \
              double mv = cand[tid];                                             \
              int rk = 0;                                                        \
              for (int j = 0; j < n; ++j){ double cj = cand[j];                  \
                rk += (cj < mv || (cj == mv && j < tid)) ? 1 : 0; }              \
              if (rk == tgt)     scD[4] = mv;                                    \
              if (rk == tgt + 1) scD[5] = mv;                                    \
            }                                                                    \
            __syncthreads();                                                     \
            break;                                                               \
          }                                                                      \
          double mid_ = 0.5 * (lo_ + hi_);                                       \
          if (!(mid_ > lo_ && mid_ < hi_)){                                      \
            if (tid == 0){ scD[4] = hi_; scD[5] = hi_; }                         \
            __syncthreads();                                                     \
            break;                                                               \
          }                                                                      \
          int c_ = 0;                                                            \
          _Pragma("unroll")                                                      \
          for (int s = 0; s < NS; ++s){                                          \
            int t = tid + (s << 10);                                             \
            if (t < TT && VALS[s] <= mid_) c_++;                                 \
          }                                                                      \
          _Pragma("unroll")                                                      \
          for (int o = 32; o; o >>= 1) c_ += __shfl_down(c_, o, 64);             \
          if (lane == 0) redI[wid] = c_;                                         \
          __syncthreads();                                                       \
          if (tid == 0){ int a = 0; for (int i = 0; i < 16; ++i) a += redI[i]; scI[6] = a; } \
          __syncthreads();                                                       \
          int ct_ = scI[6];                                                      \
          if (ct_ <= (RNK)){ lo_ = mid_; cl_ = ct_; }                            \
          else if (ct_ >= (RNK) + 2){ hi_ = mid_; ch_ = ct_; }                   \
          else {                                                                 \
            double mx_ = -1.0, mn_ = 1e300;                                      \
            _Pragma("unroll")                                                    \
            for (int s = 0; s < NS; ++s){                                        \
              int t = tid + (s << 10);                                           \
              if (t < TT){ double v = VALS[s];                                   \
                if (v <= mid_){ if (v > mx_) mx_ = v; } else { if (v < mn_) mn_ = v; } } \
            }                                                                    \
            _Pragma("unroll")                                                    \
            for (int o = 32; o; o >>= 1){ double x = __shfl_down(mx_, o, 64); if (x > mx_) mx_ = x; } \
            if (lane == 0) redD[wid] = mx_;                                      \
            __syncthreads();                                                     \
            if (tid == 0){ double a = redD[0]; for (int i = 1; i < 16; ++i) if (redD[i] > a) a = redD[i]; scD[4] = a; } \
            __syncthreads();                                                     \
            _Pragma("unroll")                                                    \
            for (int o = 32; o; o >>= 1){ double x = __shfl_down(mn_, o, 64); if (x < mn_) mn_ = x; } \
            if (lane == 0) redD[wid] = mn_;                                      \
            __syncthreads();                                                     \
            if (tid == 0){ double a = redD[0]; for (int i = 1; i < 16; ++i) if (redD[i] < a) a = redD[i]; scD[5] = a; } \
            __syncthreads();                                                     \
            break;                                                               \
          }                                                                      \
        }                                                                        \
      }                                                                          \
      if (tid == 0){                                                             \
        double d_ = scD[5] - scD[4];                                             \
        double g_ = (QG);                                                        \
        scD[OUTIDX] = (g_ >= 0.5) ? (scD[5] - d_ * (1.0 - g_)) : (scD[4] + d_ * g_); \
      }                                                                          \
      __syncthreads();                                                           \
    }                                                                            \
  }

// =================== K2: one block per row, everything fused ====================
__global__ __launch_bounds__(1024) void k_row(const double* __restrict__ e_all,
                                              float* __restrict__ out){
  __shared__ double e_s[TT];                         // 64000 B
  __shared__ double delta_s[TT];                     // 64000 B
  __shared__ __align__(16) unsigned short runs[TT];  // 16000 B (aliased as hist early)
  __shared__ unsigned char flags[TT];                //  8000 B
  __shared__ double cand[CAP];                       //  2048 B
  __shared__ double redD[64];
  __shared__ int    redI[16];
  __shared__ double scD[12];  // 0:mu 1:sd 2:dthr 3:bthr 4:vlo 5:vhi 6:maxd 7:maxb 8:tf
  __shared__ int    scI[8];   // 0:binr 1:binr1 2:Pm 3:P1 4:candN 5:fb-candN 6:fb-count
  __shared__ int    waveTot[16], waveOff[16], cnt5[5];
  int* hist = (int*)runs;     // hist lives only before runs is written

  const int b = blockIdx.x, tid = threadIdx.x;
  const int lane = tid & 63, wid = tid >> 6;
  const double* eg = e_all + (size_t)b * TT;

  if (tid < 5) cnt5[tid] = 0;

  double ev[NS], dv[NS], bv[NS];
  // ---- load e (striped) ----
  #pragma unroll
  for (int s = 0; s < NS; ++s){
    int t = tid + (s << 10);
    double e = (t < TT) ? eg[t] : 0.0;
    ev[s] = e;
    if (t < TT) e_s[t] = e;
  }
  __syncthreads();
  // ---- delta ----
  #pragma unroll
  for (int s = 0; s < NS; ++s){
    int t = tid + (s << 10);
    double d = 0.0;
    if (t > 0 && t < TT) d = fabs(e_s[t] - e_s[t-1]);
    dv[s] = d;
    if (t < TT) delta_s[t] = d;
  }
  __syncthreads();
  // ---- bs (window-7 mean), register-cached ----
  #pragma unroll
  for (int s = 0; s < NS; ++s){
    int t = tid + (s << 10);
    double sum = 0.0;
    if (t < TT){
      int j0 = t - 3; if (j0 < 0) j0 = 0;
      int j1 = t + 3; if (j1 > TT-1) j1 = TT-1;
      for (int j = j0; j <= j1; ++j) sum += delta_s[j];
    }
    bv[s] = sum / 7.0;
  }
  // ---- fused reduce: sum(e), sum(e^2), max(dv), max(bv) — one barrier round ----
  {
    double se = 0.0, s2 = 0.0, md = 0.0, mb = 0.0;
    #pragma unroll
    for (int s = 0; s < NS; ++s){
      se += ev[s]; s2 += ev[s] * ev[s];
      if (dv[s] > md) md = dv[s];
      if (bv[s] > mb) mb = bv[s];
    }
    #pragma unroll
    for (int o = 32; o; o >>= 1){
      se += __shfl_down(se, o, 64);
      s2 += __shfl_down(s2, o, 64);
      double x = __shfl_down(md, o, 64); if (x > md) md = x;
      x = __shfl_down(mb, o, 64); if (x > mb) mb = x;
    }
    if (lane == 0){ redD[wid] = se; redD[16+wid] = s2; redD[32+wid] = md; redD[48+wid] = mb; }
    __syncthreads();
    if (tid == 0){
      double a = 0, q = 0, c = 0, d2 = 0;
      for (int i = 0; i < 16; ++i){
        a += redD[i]; q += redD[16+i];
        if (redD[32+i] > c) c = redD[32+i];
        if (redD[48+i] > d2) d2 = redD[48+i];
      }
      double mu0 = a / 8000.0;
      double var = (q - a * a / 8000.0) / 7999.0;
      if (var < 0.0) var = 0.0;
      double sd0 = sqrt(var); if (sd0 < 1e-6) sd0 = 1e-6;
      scD[0] = mu0; scD[1] = sd0; scD[6] = c; scD[7] = d2;
    }
    __syncthreads();
  }
  const double mu = scD[0], sd = scD[1];

  // ---- exact quantiles (ranks 2799/2800 and 5999/6000) ----
  QUANT(dv, 2799, 2, (0.35 * 7999.0 - 2799.0), 6);
  QUANT(bv, 5999, 3, (0.75 * 7999.0 - 5999.0), 7);
  const double dthr = scD[2], bthr = scD[3];

  // ---- flags (striped, register inputs) ----
  #pragma unroll
  for (int s = 0; s < NS; ++s){
    int t = tid + (s << 10);
    if (t < TT){
      double z = (ev[s] - mu) / sd;
      bool pause  = (z <= -0.5) && (dv[s] <= dthr);
      bool voiced = (z > -0.1);
      bool bev    = (bv[s] >= bthr);
      flags[t] = (unsigned char)((pause ? 1 : 0) | (voiced ? 2 : 0) | (bev ? 4 : 0));
    }
  }
  __syncthreads();
  // ---- counts (wave-reduced, leader atomics) ----
  {
    int cp = 0, crp = 0, crs = 0, cv = 0, cb = 0;
    #pragma unroll
    for (int s = 0; s < NS; ++s){
      int t = tid + (s << 10);
      if (t < TT){
        unsigned f = flags[t];
        bool pause = (f & 1) != 0;
        bool prevP = (t > 0) ? ((flags[t-1] & 1) != 0) : false;
        cp += pause ? 1 : 0; cv += (f >> 1) & 1; cb += (f >> 2) & 1;
        if (pause && (t == 0 || !prevP)) crp++;
        if (!pause && (t == 0 || prevP)) crs++;
      }
    }
    #pragma unroll
    for (int o = 32; o; o >>= 1){
      cp += __shfl_down(cp, o, 64); crp += __shfl_down(crp, o, 64);
      crs += __shfl_down(crs, o, 64); cv += __shfl_down(cv, o, 64);
      cb += __shfl_down(cb, o, 64);
    }
    if (lane == 0){
      atomicAdd(&cnt5[0], cp); atomicAdd(&cnt5[1], crp); atomicAdd(&cnt5[2], crs);
      atomicAdd(&cnt5[3], cv); atomicAdd(&cnt5[4], cb);
    }
  }
  // ---- speech inclusive scan (contiguous-8 per thread) ----
  const int t0 = tid * 8;
  int local_speech = 0;
  if (t0 < TT){
    #pragma unroll
    for (int k = 0; k < 8; ++k) local_speech += (flags[t0 + k] & 1) ? 0 : 1;
  }
  int inc = local_speech;
  #pragma unroll
  for (int d = 1; d < 64; d <<= 1){
    int nb = __shfl_up(inc, d, 64);
    if (lane >= d) inc += nb;
  }
  if (lane == 63) waveTot[wid] = inc;
  __syncthreads();
  if (tid == 0){
    int acc = 0;
    for (int w2 = 0; w2 < 16; ++w2){ waveOff[w2] = acc; acc += waveTot[w2]; }
    scD[8] = (acc > 1) ? (double)acc : 1.0;
  }
  __syncthreads();
  const double tf = scD[8];
  if (t0 < TT){
    int run = waveOff[wid] + (inc - local_speech);
    #pragma unroll
    for (int k = 0; k < 8; ++k){
      int t = t0 + k;
      run += (flags[t] & 1) ? 0 : 1;
      runs[t] = (unsigned short)run;
    }
  }
  __syncthreads();
  // ---- stats ----
  if (tid == 0){
    float onesP = (float)cnt5[0];
    float onesS = (float)(TT - cnt5[0]);
    float* st = out + b * 6;
    st[0] = onesP / 8000.0f;
    st[1] = (cnt5[1] > 0) ? (onesP / fmaxf((float)cnt5[1], 1.0f)) : 0.0f;
    st[2] = (cnt5[2] > 0) ? (onesS / fmaxf((float)cnt5[2], 1.0f)) : 0.0f;
    st[3] = (float)((delta_s[7997] + delta_s[7998] + delta_s[7999]) / 5.0
                  - (delta_s[0] + delta_s[1] + delta_s[2]) / 5.0);
    st[4] = ((float)cnt5[4]) / 8000.0f;
    st[5] = ((float)cnt5[3]) / 8000.0f;
  }
  // ---- trace: searchsorted + lerp ----
  if (tid < NBINS){
    double target = (tid == NBINS - 1) ? 1.0 : (double)tid * (1.0 / 23.0);
    int lo2 = 0, hi2 = TT;
    while (lo2 < hi2){
      int mid = (lo2 + hi2) >> 1;
      if ((double)runs[mid] / tf < target) lo2 = mid + 1; else hi2 = mid;
    }
    int right = lo2;
    int li = right - 1; if (li < 0) li = 0; if (li > TT-1) li = TT-1;
    int ri = right;     if (ri < 0) ri = 0; if (ri > TT-1) ri = TT-1;
    double pl = (double)runs[li] / tf, pr = (double)runs[ri] / tf;
    double denom = fabs(pr - pl); if (denom < 1e-6) denom = 1e-6;
    double alpha = (target - pl) / denom;
    if (alpha < 0.0) alpha = 0.0;
    if (alpha > 1.0) alpha = 1.0;
    if (right <= 0) alpha = 0.0;
    else if (right >= TT) alpha = 1.0;
    double fL[5], fR[5];
    for (int sdx = 0; sdx < 2; ++sdx){
      int i = sdx ? ri : li;
      double* f = sdx ? fR : fL;
      unsigned fl = flags[i];
      int j0 = i - 2; if (j0 < 0) j0 = 0;
      int j1 = i + 2; if (j1 > TT-1) j1 = TT-1;
      double ws = 0.0;
      for (int j = j0; j <= j1; ++j) ws += delta_s[j];
      f[0] = (fl & 1) ? 1.0 : 0.0;
      f[1] = ws / 5.0;
      f[2] = (fl & 4) ? 1.0 : 0.0;
      double u = (i == TT - 1) ? 1.0 : (double)i * (1.0 / 7999.0);
      f[3] = (double)runs[i] / tf - u;
      f[4] = (fl & 2) ? 1.0 : 0.0;
    }
    double om = 1.0 - alpha;
    float* tr = out + BB * 6 + ((size_t)b * NBINS + tid) * 5;
    #pragma unroll
    for (int f = 0; f < 5; ++f)
      tr[f] = (float)(fL[f] * om + fR[f] * alpha);
  }
}

extern "C" void kernel_launch(void* const* d_in, const int* in_sizes, int n_in,
                              void* d_out, int out_size, void* d_ws, size_t ws_size,
                              hipStream_t stream){
  const float* mel = (const float*)d_in[0];
  float* out = (float*)d_out;
  double* e_bt = (double*)d_ws;      // 512000 doubles = 4 MB

  hipLaunchKernelGGL(k_energy, dim3(8000), dim3(256),  0, stream, mel, e_bt);
  hipLaunchKernelGGL(k_row,    dim3(BB),   dim3(1024), 0, stream, e_bt, out);
}